// Round 1
// baseline (4417.093 us; speedup 1.0000x reference)
//
#include <hip/hip_runtime.h>
#include <math.h>

#define B_  8
#define C_  512
#define N_  3136
#define IC_ 256

// ---------------------------------------------------------------------------
// Kernel 1: fused QKV projection.
// out[b][n][i] = sum_c x[b][c][n] * W[i][c] + bias[i]   (out token-major [B,N,IC])
// Tiled fp32 GEMM: 64(n) x 64(i) tile, BK=16, 256 threads, 4x4 micro-tile.
// ---------------------------------------------------------------------------
__global__ __launch_bounds__(256) void qkv_kernel(
    const float* __restrict__ x,
    const float* __restrict__ tw, const float* __restrict__ tb,
    const float* __restrict__ pw, const float* __restrict__ pb,
    const float* __restrict__ gw, const float* __restrict__ gb,
    float* __restrict__ Q, float* __restrict__ K, float* __restrict__ V)
{
    const int n0 = blockIdx.x * 64;
    const int i0 = blockIdx.y * 64;
    const int b  = blockIdx.z / 3;
    const int proj = blockIdx.z % 3;
    const float* W    = (proj == 0) ? tw : (proj == 1) ? pw : gw;
    const float* bias = (proj == 0) ? tb : (proj == 1) ? pb : gb;
    float* out        = (proj == 0) ? Q  : (proj == 1) ? K  : V;

    __shared__ float As[16][68];  // x tile:  As[c][n]  (pad 4 keeps 16B row alignment, 2-way max on store)
    __shared__ float Bs[16][68];  // W tile:  Bs[c][i]

    const int tid = threadIdx.x;
    const int tx = tid & 15;   // i micro col group
    const int ty = tid >> 4;   // n micro row group

    float acc[4][4];
#pragma unroll
    for (int r = 0; r < 4; ++r)
#pragma unroll
        for (int s = 0; s < 4; ++s) acc[r][s] = 0.f;

    for (int c0 = 0; c0 < C_; c0 += 16) {
#pragma unroll
        for (int e = 0; e < 4; ++e) {
            const int lin = tid + e * 256;
            const int r   = lin >> 6, col = lin & 63;          // x: 16 c-rows x 64 n-cols
            As[r][col] = x[((size_t)b * C_ + (c0 + r)) * N_ + n0 + col];
            const int il = lin >> 4, cc = lin & 15;            // W: 64 i-rows x 16 c-cols
            Bs[cc][il] = W[(size_t)(i0 + il) * C_ + c0 + cc];
        }
        __syncthreads();
#pragma unroll
        for (int k = 0; k < 16; ++k) {
            float a[4], w4[4];
#pragma unroll
            for (int r = 0; r < 4; ++r) a[r] = As[k][ty * 4 + r];
#pragma unroll
            for (int s = 0; s < 4; ++s) w4[s] = Bs[k][tx * 4 + s];
#pragma unroll
            for (int r = 0; r < 4; ++r)
#pragma unroll
                for (int s = 0; s < 4; ++s) acc[r][s] += a[r] * w4[s];
        }
        __syncthreads();
    }

    const float4 bv = *(const float4*)&bias[i0 + tx * 4];
#pragma unroll
    for (int r = 0; r < 4; ++r) {
        float4 o;
        o.x = acc[r][0] + bv.x; o.y = acc[r][1] + bv.y;
        o.z = acc[r][2] + bv.z; o.w = acc[r][3] + bv.w;
        *(float4*)&out[((size_t)b * N_ + (n0 + ty * 4 + r)) * IC_ + i0 + tx * 4] = o;
    }
}

// ---------------------------------------------------------------------------
// Kernel 2: flash attention (fp32, online softmax). No S matrix materialized.
// Block = 256 threads = 64 q-rows; 4 lanes per row, each owning 64 of 256 dims.
// K/V streamed through LDS in 32-row tiles. LDS reads use a (jj+tg)&15 float4
// rotation so the 4 lane-groups hit 4 distinct bank quads (conflict-free);
// register arrays are only ever statically indexed (no scratch).
// ---------------------------------------------------------------------------
__global__ __launch_bounds__(256, 2) void attn_kernel(
    const float* __restrict__ Q, const float* __restrict__ K,
    const float* __restrict__ V, float* __restrict__ Y)
{
    const int q0  = blockIdx.x * 64;
    const int b   = blockIdx.y;
    const int tid = threadIdx.x;
    const int qr  = tid >> 2;   // local q row 0..63
    const int tg  = tid & 3;    // column group: dims [tg*64, tg*64+64)

    const float* Qb = Q + (size_t)b * N_ * IC_;
    const float* Kb = K + (size_t)b * N_ * IC_;
    const float* Vb = V + (size_t)b * N_ * IC_;

    __shared__ float Ks[32][IC_];  // 32 KB
    __shared__ float Vs[32][IC_];  // 32 KB

    // Q row fragment, loaded in rotated order (consistent with LDS-read rotation)
    float4 qreg[16];
    const float4* qrow = (const float4*)(Qb + (size_t)(q0 + qr) * IC_ + tg * 64);
#pragma unroll
    for (int jj = 0; jj < 16; ++jj) qreg[jj] = qrow[(jj + tg) & 15];

    float acc[64];
#pragma unroll
    for (int j = 0; j < 64; ++j) acc[j] = 0.f;
    float m = -1e30f, l = 0.f;

    for (int k0 = 0; k0 < N_; k0 += 32) {
        const float4* Kg  = (const float4*)(Kb + (size_t)k0 * IC_);
        const float4* Vg  = (const float4*)(Vb + (size_t)k0 * IC_);
        float4* Ksv = (float4*)&Ks[0][0];
        float4* Vsv = (float4*)&Vs[0][0];
#pragma unroll
        for (int e = 0; e < 8; ++e) {
            Ksv[tid + e * 256] = Kg[tid + e * 256];
            Vsv[tid + e * 256] = Vg[tid + e * 256];
        }
        __syncthreads();

        // --- QK^T: 32 logits per row ---
        float s[32];
#pragma unroll
        for (int kk = 0; kk < 32; ++kk) {
            const float4* kr = (const float4*)&Ks[kk][tg * 64];
            float d = 0.f;
#pragma unroll
            for (int jj = 0; jj < 16; ++jj) {
                const float4 kv = kr[(jj + tg) & 15];
                d += qreg[jj].x * kv.x + qreg[jj].y * kv.y
                   + qreg[jj].z * kv.z + qreg[jj].w * kv.w;
            }
            d += __shfl_xor(d, 1);
            d += __shfl_xor(d, 2);
            s[kk] = d;             // all 4 lanes of the row hold the full logit
        }

        // --- online softmax update ---
        float tmax = s[0];
#pragma unroll
        for (int kk = 1; kk < 32; ++kk) tmax = fmaxf(tmax, s[kk]);
        const float mnew  = fmaxf(m, tmax);
        const float scale = __expf(m - mnew);
        float psum = 0.f;
#pragma unroll
        for (int kk = 0; kk < 32; ++kk) { s[kk] = __expf(s[kk] - mnew); psum += s[kk]; }
        l = l * scale + psum;
        m = mnew;
#pragma unroll
        for (int j = 0; j < 64; ++j) acc[j] *= scale;

        // --- PV accumulate ---
#pragma unroll
        for (int kk = 0; kk < 32; ++kk) {
            const float4* vr = (const float4*)&Vs[kk][tg * 64];
            const float p = s[kk];
#pragma unroll
            for (int jj = 0; jj < 16; ++jj) {
                const float4 vv = vr[(jj + tg) & 15];
                acc[jj * 4 + 0] += p * vv.x;
                acc[jj * 4 + 1] += p * vv.y;
                acc[jj * 4 + 2] += p * vv.z;
                acc[jj * 4 + 3] += p * vv.w;
            }
        }
        __syncthreads();
    }

    const float inv = 1.f / l;
    float4* yrow = (float4*)(Y + ((size_t)b * N_ + q0 + qr) * IC_ + tg * 64);
#pragma unroll
    for (int jj = 0; jj < 16; ++jj) {
        float4 o;
        o.x = acc[jj * 4 + 0] * inv; o.y = acc[jj * 4 + 1] * inv;
        o.z = acc[jj * 4 + 2] * inv; o.w = acc[jj * 4 + 3] * inv;
        yrow[(jj + tg) & 15] = o;
    }
}

// ---------------------------------------------------------------------------
// Kernel 3: wz projection. Z[b][c][n] = sum_i Y[b][n][i] * wz_w[c][i] + wz_b[c]
// Output written channel-major straight into d_out (used as Z scratch).
// ---------------------------------------------------------------------------
__global__ __launch_bounds__(256) void wz_kernel(
    const float* __restrict__ Y, const float* __restrict__ wzw,
    const float* __restrict__ wzb, float* __restrict__ Z)
{
    const int n0 = blockIdx.x * 64;
    const int c0 = blockIdx.y * 64;
    const int b  = blockIdx.z;

    __shared__ float As[16][68];  // wz_w tile: As[i][c]
    __shared__ float Bs[16][68];  // Y tile:    Bs[i][n]

    const int tid = threadIdx.x;
    const int tx = tid & 15;   // n micro col group
    const int ty = tid >> 4;   // c micro row group

    float acc[4][4];
#pragma unroll
    for (int r = 0; r < 4; ++r)
#pragma unroll
        for (int s = 0; s < 4; ++s) acc[r][s] = 0.f;

    for (int k0 = 0; k0 < IC_; k0 += 16) {
#pragma unroll
        for (int e = 0; e < 4; ++e) {
            const int lin = tid + e * 256;
            const int row = lin >> 4, ii = lin & 15;           // 64 rows x 16 i-cols
            As[ii][row] = wzw[(size_t)(c0 + row) * IC_ + k0 + ii];
            Bs[ii][row] = Y[((size_t)b * N_ + (n0 + row)) * IC_ + k0 + ii];
        }
        __syncthreads();
#pragma unroll
        for (int k = 0; k < 16; ++k) {
            float a[4], yv[4];
#pragma unroll
            for (int r = 0; r < 4; ++r) a[r] = As[k][ty * 4 + r];
#pragma unroll
            for (int s = 0; s < 4; ++s) yv[s] = Bs[k][tx * 4 + s];
#pragma unroll
            for (int r = 0; r < 4; ++r)
#pragma unroll
                for (int s = 0; s < 4; ++s) acc[r][s] += a[r] * yv[s];
        }
        __syncthreads();
    }

#pragma unroll
    for (int r = 0; r < 4; ++r) {
        const float br = wzb[c0 + ty * 4 + r];
        float4 o;
        o.x = acc[r][0] + br; o.y = acc[r][1] + br;
        o.z = acc[r][2] + br; o.w = acc[r][3] + br;
        *(float4*)&Z[((size_t)b * C_ + (c0 + ty * 4 + r)) * N_ + n0 + tx * 4] = o;
    }
}

// ---------------------------------------------------------------------------
// Kernel 4: per-channel batch stats over (B, N). Biased variance, double accum.
// ---------------------------------------------------------------------------
__global__ __launch_bounds__(256) void bn_stats_kernel(
    const float* __restrict__ Z, float* __restrict__ stats)
{
    const int c   = blockIdx.x;
    const int tid = threadIdx.x;
    double s = 0.0, s2 = 0.0;
    for (int b = 0; b < B_; ++b) {
        const float* p = Z + ((size_t)b * C_ + c) * N_;
        for (int n = tid; n < N_; n += 256) {
            const double v = (double)p[n];
            s += v; s2 += v * v;
        }
    }
    __shared__ double ls[256], ls2[256];
    ls[tid] = s; ls2[tid] = s2;
    __syncthreads();
    for (int off = 128; off > 0; off >>= 1) {
        if (tid < off) { ls[tid] += ls[tid + off]; ls2[tid] += ls2[tid + off]; }
        __syncthreads();
    }
    if (tid == 0) {
        const double M    = (double)B_ * (double)N_;
        const double mean = ls[0] / M;
        const double var  = ls2[0] / M - mean * mean;
        stats[c]      = (float)mean;
        stats[C_ + c] = (float)var;
    }
}

// ---------------------------------------------------------------------------
// Kernel 5: BN apply + residual, in place on d_out (reads Z==out, writes out).
// ---------------------------------------------------------------------------
__global__ __launch_bounds__(256) void bn_apply_kernel(
    const float* __restrict__ Z, const float* __restrict__ x,
    const float* __restrict__ stats,
    const float* __restrict__ bnw, const float* __restrict__ bnb,
    float* __restrict__ out)
{
    const size_t total4 = (size_t)B_ * C_ * N_ / 4;
    const size_t i4 = (size_t)blockIdx.x * blockDim.x + threadIdx.x;
    if (i4 >= total4) return;
    const size_t i = i4 * 4;
    const int c = (int)((i / N_) % C_);
    const float mean = stats[c];
    const float var  = stats[C_ + c];
    const float sc = rsqrtf(var + 1e-5f) * bnw[c];
    const float sh = bnb[c] - mean * sc;
    const float4 z  = ((const float4*)Z)[i4];
    const float4 xv = ((const float4*)x)[i4];
    float4 o;
    o.x = z.x * sc + sh + xv.x;
    o.y = z.y * sc + sh + xv.y;
    o.z = z.z * sc + sh + xv.z;
    o.w = z.w * sc + sh + xv.w;
    ((float4*)out)[i4] = o;
}

// ---------------------------------------------------------------------------
extern "C" void kernel_launch(void* const* d_in, const int* in_sizes, int n_in,
                              void* d_out, int out_size, void* d_ws, size_t ws_size,
                              hipStream_t stream)
{
    const float* x   = (const float*)d_in[0];
    const float* tw  = (const float*)d_in[1];
    const float* tb  = (const float*)d_in[2];
    const float* pw  = (const float*)d_in[3];
    const float* pb  = (const float*)d_in[4];
    const float* gw  = (const float*)d_in[5];
    const float* gb  = (const float*)d_in[6];
    const float* wzw = (const float*)d_in[7];
    const float* wzb = (const float*)d_in[8];
    const float* bnw = (const float*)d_in[9];
    const float* bnb = (const float*)d_in[10];
    float* out = (float*)d_out;

    float* ws = (float*)d_ws;
    const size_t NIC = (size_t)B_ * N_ * IC_;   // 6,422,528 floats
    float* Qb    = ws;                           // [B,N,IC]
    float* Kb    = Qb + NIC;
    float* Vb    = Kb + NIC;
    float* Yb    = Vb + NIC;
    float* stats = Yb + NIC;                     // 2*C_ floats
    float* Zb    = out;                          // d_out doubles as Z scratch

    qkv_kernel<<<dim3(N_ / 64, IC_ / 64, B_ * 3), 256, 0, stream>>>(
        x, tw, tb, pw, pb, gw, gb, Qb, Kb, Vb);
    attn_kernel<<<dim3(N_ / 64, B_), 256, 0, stream>>>(Qb, Kb, Vb, Yb);
    wz_kernel<<<dim3(N_ / 64, C_ / 64, B_), 256, 0, stream>>>(Yb, wzw, wzb, Zb);
    bn_stats_kernel<<<C_, 256, 0, stream>>>(Zb, stats);
    const int total4 = B_ * C_ * N_ / 4;
    bn_apply_kernel<<<(total4 + 255) / 256, 256, 0, stream>>>(Zb, x, stats, bnw, bnb, out);
}

// Round 2
// 1105.317 us; speedup vs baseline: 3.9962x; 3.9962x over previous
//
#include <hip/hip_runtime.h>
#include <math.h>

#define B_  8
#define C_  512
#define N_  3136
#define IC_ 256

typedef __attribute__((ext_vector_type(8))) short bf16x8;
typedef __attribute__((ext_vector_type(4))) float f32x4;

static __device__ __forceinline__ unsigned short f2bf(float f) {
    unsigned int u = __builtin_bit_cast(unsigned int, f);
    u = (u + 0x7fffu + ((u >> 16) & 1u)) >> 16;   // RNE
    return (unsigned short)u;
}

// ---------------------------------------------------------------------------
// Kernel 1: fused QKV projection (fp32 math, bf16 outputs).
// Q,K: [B,N,IC] bf16 row-major.  V: transposed -> Vt [B,IC,N] bf16.
// ---------------------------------------------------------------------------
__global__ __launch_bounds__(256) void qkv_kernel(
    const float* __restrict__ x,
    const float* __restrict__ tw, const float* __restrict__ tb,
    const float* __restrict__ pw, const float* __restrict__ pb,
    const float* __restrict__ gw, const float* __restrict__ gb,
    unsigned short* __restrict__ Q, unsigned short* __restrict__ K,
    unsigned short* __restrict__ Vt)
{
    const int n0 = blockIdx.x * 64;
    const int i0 = blockIdx.y * 64;
    const int b  = blockIdx.z / 3;
    const int proj = blockIdx.z % 3;
    const float* W    = (proj == 0) ? tw : (proj == 1) ? pw : gw;
    const float* bias = (proj == 0) ? tb : (proj == 1) ? pb : gb;

    __shared__ float As[16][68];  // x tile:  As[c][n]
    __shared__ float Bs[16][68];  // W tile:  Bs[c][i]

    const int tid = threadIdx.x;
    const int tx = tid & 15;   // i micro col group
    const int ty = tid >> 4;   // n micro row group

    float acc[4][4];
#pragma unroll
    for (int r = 0; r < 4; ++r)
#pragma unroll
        for (int s = 0; s < 4; ++s) acc[r][s] = 0.f;

    for (int c0 = 0; c0 < C_; c0 += 16) {
#pragma unroll
        for (int e = 0; e < 4; ++e) {
            const int lin = tid + e * 256;
            const int r   = lin >> 6, col = lin & 63;
            As[r][col] = x[((size_t)b * C_ + (c0 + r)) * N_ + n0 + col];
            const int il = lin >> 4, cc = lin & 15;
            Bs[cc][il] = W[(size_t)(i0 + il) * C_ + c0 + cc];
        }
        __syncthreads();
#pragma unroll
        for (int k = 0; k < 16; ++k) {
            float a[4], w4[4];
#pragma unroll
            for (int r = 0; r < 4; ++r) a[r] = As[k][ty * 4 + r];
#pragma unroll
            for (int s = 0; s < 4; ++s) w4[s] = Bs[k][tx * 4 + s];
#pragma unroll
            for (int r = 0; r < 4; ++r)
#pragma unroll
                for (int s = 0; s < 4; ++s) acc[r][s] += a[r] * w4[s];
        }
        __syncthreads();
    }

    const float4 bv = *(const float4*)&bias[i0 + tx * 4];
    if (proj == 2) {
        // V: write transposed Vt[b][i][n], scalar bf16 stores
#pragma unroll
        for (int r = 0; r < 4; ++r) {
            const float bvv[4] = {bv.x, bv.y, bv.z, bv.w};
#pragma unroll
            for (int s = 0; s < 4; ++s)
                Vt[((size_t)b * IC_ + (i0 + tx * 4 + s)) * N_ + n0 + ty * 4 + r] =
                    f2bf(acc[r][s] + bvv[s]);
        }
    } else {
        unsigned short* out = (proj == 0) ? Q : K;
#pragma unroll
        for (int r = 0; r < 4; ++r) {
            ushort4 o;
            o.x = f2bf(acc[r][0] + bv.x); o.y = f2bf(acc[r][1] + bv.y);
            o.z = f2bf(acc[r][2] + bv.z); o.w = f2bf(acc[r][3] + bv.w);
            *(ushort4*)&out[((size_t)b * N_ + (n0 + ty * 4 + r)) * IC_ + i0 + tx * 4] = o;
        }
    }
}

// ---------------------------------------------------------------------------
// Kernel 2: MFMA flash attention (bf16 inputs, fp32 accum/softmax).
// Block = 256 threads = 4 waves; each wave owns 16 q-rows; KVBLK = 64.
// mfma_f32_16x16x32_bf16:
//   A lane l: row=l&15,          k=(l>>4)*8+j  (16B contiguous from row-major)
//   B lane l: col=l&15,          k=(l>>4)*8+j  (16B contiguous from K rows / Vt rows)
//   D lane l: col=l&15, row=(l>>4)*4+reg
// P staged per-wave in XOR-swizzled LDS (no cross-wave deps -> no barriers).
// Grid (B, N/64): blockIdx.x = batch so each XCD L2-caches one batch's K/Vt.
// ---------------------------------------------------------------------------
__global__ __launch_bounds__(256, 2) void attn_kernel(
    const unsigned short* __restrict__ Q, const unsigned short* __restrict__ K,
    const unsigned short* __restrict__ Vt, float* __restrict__ Y)
{
    const int b    = blockIdx.x;
    const int q0   = blockIdx.y * 64;
    const int tid  = threadIdx.x;
    const int wq   = tid >> 6;       // wave 0..3
    const int lane = tid & 63;
    const int g    = lane >> 4;      // 0..3
    const int c    = lane & 15;      // 0..15

    const unsigned short* Qb = Q  + (size_t)b * N_ * IC_;
    const unsigned short* Kb = K  + (size_t)b * N_ * IC_;
    const unsigned short* Vb = Vt + (size_t)b * IC_ * N_;

    __shared__ unsigned short P_lds[4][16 * 64];   // 2 KB per wave

    // hoist Q fragments: wave's q-rows are q0+wq*16 .. +15; A-frag row = c
    bf16x8 qf[8];
    {
        const unsigned short* qrow = &Qb[(size_t)(q0 + wq * 16 + c) * IC_ + g * 8];
#pragma unroll
        for (int dc = 0; dc < 8; ++dc)
            qf[dc] = *(const bf16x8*)&qrow[dc * 32];
    }

    f32x4 yacc[16];
#pragma unroll
    for (int ds = 0; ds < 16; ++ds) yacc[ds] = (f32x4){0.f, 0.f, 0.f, 0.f};
    float m[4]    = {-1e30f, -1e30f, -1e30f, -1e30f};
    float lsum[4] = {0.f, 0.f, 0.f, 0.f};

    for (int k0 = 0; k0 < N_; k0 += 64) {
        // ---- QK^T: S[16 q][64 k] ----
        f32x4 sacc[4];
#pragma unroll
        for (int ks = 0; ks < 4; ++ks) sacc[ks] = (f32x4){0.f, 0.f, 0.f, 0.f};
#pragma unroll
        for (int ks = 0; ks < 4; ++ks) {
            const unsigned short* krow = &Kb[(size_t)(k0 + ks * 16 + c) * IC_ + g * 8];
#pragma unroll
            for (int dc = 0; dc < 8; ++dc) {
                const bf16x8 kf = *(const bf16x8*)&krow[dc * 32];
                sacc[ks] = __builtin_amdgcn_mfma_f32_16x16x32_bf16(qf[dc], kf, sacc[ks], 0, 0, 0);
            }
        }

        // ---- online softmax (lane owns rows q=4g+r, cols k=16ks+c) ----
        float mnew[4], sc[4], rsum[4];
#pragma unroll
        for (int r = 0; r < 4; ++r) {
            float rm = fmaxf(fmaxf(sacc[0][r], sacc[1][r]), fmaxf(sacc[2][r], sacc[3][r]));
            rm = fmaxf(rm, __shfl_xor(rm, 1));
            rm = fmaxf(rm, __shfl_xor(rm, 2));
            rm = fmaxf(rm, __shfl_xor(rm, 4));
            rm = fmaxf(rm, __shfl_xor(rm, 8));
            mnew[r] = fmaxf(m[r], rm);
            sc[r]   = __expf(m[r] - mnew[r]);
            m[r]    = mnew[r];
            rsum[r] = 0.f;
        }
        float p[4][4];
#pragma unroll
        for (int ks = 0; ks < 4; ++ks)
#pragma unroll
            for (int r = 0; r < 4; ++r) {
                p[ks][r] = __expf(sacc[ks][r] - mnew[r]);
                rsum[r] += p[ks][r];
            }
#pragma unroll
        for (int r = 0; r < 4; ++r) {
            rsum[r] += __shfl_xor(rsum[r], 1);
            rsum[r] += __shfl_xor(rsum[r], 2);
            rsum[r] += __shfl_xor(rsum[r], 4);
            rsum[r] += __shfl_xor(rsum[r], 8);
            lsum[r] = lsum[r] * sc[r] + rsum[r];
        }
        // rescale running output
#pragma unroll
        for (int ds = 0; ds < 16; ++ds)
#pragma unroll
            for (int r = 0; r < 4; ++r) yacc[ds][r] *= sc[r];

        // ---- P -> LDS (bf16, XOR-swizzled rows) ----
#pragma unroll
        for (int ks = 0; ks < 4; ++ks)
#pragma unroll
            for (int r = 0; r < 4; ++r) {
                const int q = 4 * g + r;
                const int k = ks * 16 + c;
                P_lds[wq][q * 64 + (k ^ ((q & 7) << 3))] = f2bf(p[ks][r]);
            }

        // ---- PV: Y += P[16x64] * V[64 k][256 d]  (B from Vt rows) ----
#pragma unroll
        for (int kc = 0; kc < 2; ++kc) {
            const bf16x8 pf =
                *(const bf16x8*)&P_lds[wq][c * 64 + ((kc * 32 + g * 8) ^ ((c & 7) << 3))];
#pragma unroll
            for (int ds = 0; ds < 16; ++ds) {
                const bf16x8 vf =
                    *(const bf16x8*)&Vb[(size_t)(ds * 16 + c) * N_ + k0 + kc * 32 + g * 8];
                yacc[ds] = __builtin_amdgcn_mfma_f32_16x16x32_bf16(pf, vf, yacc[ds], 0, 0, 0);
            }
        }
    }

    // ---- epilogue: normalize, write Y fp32 [B,N,IC] ----
    float inv[4];
#pragma unroll
    for (int r = 0; r < 4; ++r) inv[r] = 1.f / lsum[r];
#pragma unroll
    for (int ds = 0; ds < 16; ++ds)
#pragma unroll
        for (int r = 0; r < 4; ++r)
            Y[((size_t)b * N_ + q0 + wq * 16 + 4 * g + r) * IC_ + ds * 16 + c] =
                yacc[ds][r] * inv[r];
}

// ---------------------------------------------------------------------------
// Kernel 3: wz projection. Z[b][c][n] = sum_i Y[b][n][i] * wz_w[c][i] + wz_b[c]
// ---------------------------------------------------------------------------
__global__ __launch_bounds__(256) void wz_kernel(
    const float* __restrict__ Y, const float* __restrict__ wzw,
    const float* __restrict__ wzb, float* __restrict__ Z)
{
    const int n0 = blockIdx.x * 64;
    const int c0 = blockIdx.y * 64;
    const int b  = blockIdx.z;

    __shared__ float As[16][68];
    __shared__ float Bs[16][68];

    const int tid = threadIdx.x;
    const int tx = tid & 15;
    const int ty = tid >> 4;

    float acc[4][4];
#pragma unroll
    for (int r = 0; r < 4; ++r)
#pragma unroll
        for (int s = 0; s < 4; ++s) acc[r][s] = 0.f;

    for (int k0 = 0; k0 < IC_; k0 += 16) {
#pragma unroll
        for (int e = 0; e < 4; ++e) {
            const int lin = tid + e * 256;
            const int row = lin >> 4, ii = lin & 15;
            As[ii][row] = wzw[(size_t)(c0 + row) * IC_ + k0 + ii];
            Bs[ii][row] = Y[((size_t)b * N_ + (n0 + row)) * IC_ + k0 + ii];
        }
        __syncthreads();
#pragma unroll
        for (int k = 0; k < 16; ++k) {
            float a[4], yv[4];
#pragma unroll
            for (int r = 0; r < 4; ++r) a[r] = As[k][ty * 4 + r];
#pragma unroll
            for (int s = 0; s < 4; ++s) yv[s] = Bs[k][tx * 4 + s];
#pragma unroll
            for (int r = 0; r < 4; ++r)
#pragma unroll
                for (int s = 0; s < 4; ++s) acc[r][s] += a[r] * yv[s];
        }
        __syncthreads();
    }

#pragma unroll
    for (int r = 0; r < 4; ++r) {
        const float br = wzb[c0 + ty * 4 + r];
        float4 o;
        o.x = acc[r][0] + br; o.y = acc[r][1] + br;
        o.z = acc[r][2] + br; o.w = acc[r][3] + br;
        *(float4*)&Z[((size_t)b * C_ + (c0 + ty * 4 + r)) * N_ + n0 + tx * 4] = o;
    }
}

// ---------------------------------------------------------------------------
// Kernel 4: per-channel batch stats (biased variance, double accum).
// ---------------------------------------------------------------------------
__global__ __launch_bounds__(256) void bn_stats_kernel(
    const float* __restrict__ Z, float* __restrict__ stats)
{
    const int c   = blockIdx.x;
    const int tid = threadIdx.x;
    double s = 0.0, s2 = 0.0;
    for (int b = 0; b < B_; ++b) {
        const float* p = Z + ((size_t)b * C_ + c) * N_;
        for (int n = tid; n < N_; n += 256) {
            const double v = (double)p[n];
            s += v; s2 += v * v;
        }
    }
    __shared__ double ls[256], ls2[256];
    ls[tid] = s; ls2[tid] = s2;
    __syncthreads();
    for (int off = 128; off > 0; off >>= 1) {
        if (tid < off) { ls[tid] += ls[tid + off]; ls2[tid] += ls2[tid + off]; }
        __syncthreads();
    }
    if (tid == 0) {
        const double M    = (double)B_ * (double)N_;
        const double mean = ls[0] / M;
        const double var  = ls2[0] / M - mean * mean;
        stats[c]      = (float)mean;
        stats[C_ + c] = (float)var;
    }
}

// ---------------------------------------------------------------------------
// Kernel 5: BN apply + residual, in place on d_out.
// ---------------------------------------------------------------------------
__global__ __launch_bounds__(256) void bn_apply_kernel(
    const float* __restrict__ Z, const float* __restrict__ x,
    const float* __restrict__ stats,
    const float* __restrict__ bnw, const float* __restrict__ bnb,
    float* __restrict__ out)
{
    const size_t total4 = (size_t)B_ * C_ * N_ / 4;
    const size_t i4 = (size_t)blockIdx.x * blockDim.x + threadIdx.x;
    if (i4 >= total4) return;
    const size_t i = i4 * 4;
    const int c = (int)((i / N_) % C_);
    const float mean = stats[c];
    const float var  = stats[C_ + c];
    const float sc = rsqrtf(var + 1e-5f) * bnw[c];
    const float sh = bnb[c] - mean * sc;
    const float4 z  = ((const float4*)Z)[i4];
    const float4 xv = ((const float4*)x)[i4];
    float4 o;
    o.x = z.x * sc + sh + xv.x;
    o.y = z.y * sc + sh + xv.y;
    o.z = z.z * sc + sh + xv.z;
    o.w = z.w * sc + sh + xv.w;
    ((float4*)out)[i4] = o;
}

// ---------------------------------------------------------------------------
extern "C" void kernel_launch(void* const* d_in, const int* in_sizes, int n_in,
                              void* d_out, int out_size, void* d_ws, size_t ws_size,
                              hipStream_t stream)
{
    const float* x   = (const float*)d_in[0];
    const float* tw  = (const float*)d_in[1];
    const float* tb  = (const float*)d_in[2];
    const float* pw  = (const float*)d_in[3];
    const float* pb  = (const float*)d_in[4];
    const float* gw  = (const float*)d_in[5];
    const float* gb  = (const float*)d_in[6];
    const float* wzw = (const float*)d_in[7];
    const float* wzb = (const float*)d_in[8];
    const float* bnw = (const float*)d_in[9];
    const float* bnb = (const float*)d_in[10];
    float* out = (float*)d_out;

    const size_t NIC = (size_t)B_ * N_ * IC_;      // 6,422,528
    unsigned short* Qw  = (unsigned short*)d_ws;   // bf16 [B,N,IC]
    unsigned short* Kw  = Qw + NIC;                // bf16 [B,N,IC]
    unsigned short* Vtw = Kw + NIC;                // bf16 [B,IC,N]
    float* Yw    = (float*)(Vtw + NIC);            // fp32 [B,N,IC]
    float* stats = Yw + NIC;                       // 2*C_
    float* Zb    = out;                            // d_out doubles as Z scratch

    qkv_kernel<<<dim3(N_ / 64, IC_ / 64, B_ * 3), 256, 0, stream>>>(
        x, tw, tb, pw, pb, gw, gb, Qw, Kw, Vtw);
    attn_kernel<<<dim3(B_, N_ / 64), 256, 0, stream>>>(Qw, Kw, Vtw, Yw);
    wz_kernel<<<dim3(N_ / 64, C_ / 64, B_), 256, 0, stream>>>(Yw, wzw, wzb, Zb);
    bn_stats_kernel<<<C_, 256, 0, stream>>>(Zb, stats);
    const int total4 = B_ * C_ * N_ / 4;
    bn_apply_kernel<<<(total4 + 255) / 256, 256, 0, stream>>>(Zb, x, stats, bnw, bnb, out);
}

// Round 3
// 638.189 us; speedup vs baseline: 6.9213x; 1.7320x over previous
//
#include <hip/hip_runtime.h>
#include <math.h>

#define B_  8
#define C_  512
#define N_  3136
#define IC_ 256

typedef __attribute__((ext_vector_type(8))) short bf16x8;
typedef __attribute__((ext_vector_type(4))) float f32x4;

static __device__ __forceinline__ unsigned short f2bf(float f) {
    unsigned int u = __builtin_bit_cast(unsigned int, f);
    u = (u + 0x7fffu + ((u >> 16) & 1u)) >> 16;   // RNE
    return (unsigned short)u;
}

// ---------------------------------------------------------------------------
// Kernel 1: fused QKV projection (fp32 math, bf16 outputs).
// Q,K: [B,N,IC] bf16 row-major.  V: transposed -> Vt [B,IC,N] bf16
// (proj==2 transposes through LDS, coalesced 16B stores).
// ---------------------------------------------------------------------------
__global__ __launch_bounds__(256) void qkv_kernel(
    const float* __restrict__ x,
    const float* __restrict__ tw, const float* __restrict__ tb,
    const float* __restrict__ pw, const float* __restrict__ pb,
    const float* __restrict__ gw, const float* __restrict__ gb,
    unsigned short* __restrict__ Q, unsigned short* __restrict__ K,
    unsigned short* __restrict__ Vt)
{
    const int n0 = blockIdx.x * 64;
    const int i0 = blockIdx.y * 64;
    const int b  = blockIdx.z / 3;
    const int proj = blockIdx.z % 3;
    const float* W    = (proj == 0) ? tw : (proj == 1) ? pw : gw;
    const float* bias = (proj == 0) ? tb : (proj == 1) ? pb : gb;

    __shared__ float smem[2][16][68];
    float (*As)[68] = smem[0];   // x tile:  As[c][n]
    float (*Bs)[68] = smem[1];   // W tile:  Bs[c][i]

    const int tid = threadIdx.x;
    const int tx = tid & 15;   // i micro col group
    const int ty = tid >> 4;   // n micro row group

    float acc[4][4];
#pragma unroll
    for (int r = 0; r < 4; ++r)
#pragma unroll
        for (int s = 0; s < 4; ++s) acc[r][s] = 0.f;

    for (int c0 = 0; c0 < C_; c0 += 16) {
#pragma unroll
        for (int e = 0; e < 4; ++e) {
            const int lin = tid + e * 256;
            const int r   = lin >> 6, col = lin & 63;
            As[r][col] = x[((size_t)b * C_ + (c0 + r)) * N_ + n0 + col];
            const int il = lin >> 4, cc = lin & 15;
            Bs[cc][il] = W[(size_t)(i0 + il) * C_ + c0 + cc];
        }
        __syncthreads();
#pragma unroll
        for (int k = 0; k < 16; ++k) {
            float a[4], w4[4];
#pragma unroll
            for (int r = 0; r < 4; ++r) a[r] = As[k][ty * 4 + r];
#pragma unroll
            for (int s = 0; s < 4; ++s) w4[s] = Bs[k][tx * 4 + s];
#pragma unroll
            for (int r = 0; r < 4; ++r)
#pragma unroll
                for (int s = 0; s < 4; ++s) acc[r][s] += a[r] * w4[s];
        }
        __syncthreads();
    }

    const float4 bv = *(const float4*)&bias[i0 + tx * 4];
    if (proj == 2) {
        // transpose tile via LDS, store Vt rows coalesced
        unsigned short* T = (unsigned short*)&smem[0][0][0];   // [64 i][64 n]
        const float bvv[4] = {bv.x, bv.y, bv.z, bv.w};
#pragma unroll
        for (int r = 0; r < 4; ++r)
#pragma unroll
            for (int s = 0; s < 4; ++s)
                T[(tx * 4 + s) * 64 + ty * 4 + r] = f2bf(acc[r][s] + bvv[s]);
        __syncthreads();
        const int il = tid >> 2;          // i row 0..63
        const int ng = (tid & 3) * 16;    // n col group
        unsigned short* dst = &Vt[((size_t)b * IC_ + i0 + il) * N_ + n0 + ng];
        *(bf16x8*)dst       = *(const bf16x8*)&T[il * 64 + ng];
        *(bf16x8*)(dst + 8) = *(const bf16x8*)&T[il * 64 + ng + 8];
    } else {
        unsigned short* out = (proj == 0) ? Q : K;
#pragma unroll
        for (int r = 0; r < 4; ++r) {
            ushort4 o;
            o.x = f2bf(acc[r][0] + bv.x); o.y = f2bf(acc[r][1] + bv.y);
            o.z = f2bf(acc[r][2] + bv.z); o.w = f2bf(acc[r][3] + bv.w);
            *(ushort4*)&out[((size_t)b * N_ + (n0 + ty * 4 + r)) * IC_ + i0 + tx * 4] = o;
        }
    }
}

// ---------------------------------------------------------------------------
// Kernel 2: MFMA flash attention, LDS-staged K/V, reg-prefetch pipeline.
// Block = 4 waves x 16 q-rows, KVBLK = 64.
// LDS layout (16B slots, XOR-swizzled via pre-swizzled GLOBAL source + linear
// ds_write, read back with the same XOR -> conflict-free ds_read_b128):
//   Ks[64][256] bf16: row k, slot s holds data slot s^(k&7)   (32 KB)
//   Vs[256][64] bf16: row d, slot s holds data slot s^(d&7)   (32 KB)
// Per tile: issue next tile's global loads -> QK^T -> softmax -> PV ->
// barrier -> ds_write staged regs -> barrier.
// ---------------------------------------------------------------------------
__global__ __launch_bounds__(256, 2) void attn_kernel(
    const unsigned short* __restrict__ Q, const unsigned short* __restrict__ K,
    const unsigned short* __restrict__ Vt, float* __restrict__ Y)
{
    const int b    = blockIdx.x;
    const int q0   = blockIdx.y * 64;
    const int tid  = threadIdx.x;
    const int wq   = tid >> 6;       // wave 0..3
    const int lane = tid & 63;
    const int g    = lane >> 4;      // 0..3
    const int c    = lane & 15;      // 0..15

    const unsigned short* Qb = Q  + (size_t)b * N_ * IC_;
    const unsigned short* Kb = K  + (size_t)b * N_ * IC_;
    const unsigned short* Vb = Vt + (size_t)b * IC_ * N_;

    __shared__ unsigned short Ks[64 * 256];        // 32 KB
    __shared__ unsigned short Vs[256 * 64];        // 32 KB
    __shared__ unsigned short P_lds[4][16 * 64];   // 8 KB

    // staging index helpers (per-thread constants)
    const int krw = tid >> 5;                 // K row base 0..7 (+8e)
    const int ksl = tid & 31;                 // K 16B slot in 512B row
    const int ksl_g = ksl ^ krw;              // pre-swizzled source slot (row&7 == krw)
    const int vrw = tid >> 3;                 // V row base 0..31 (+32e)
    const int vsl = tid & 7;                  // V 16B slot in 128B row
    const int vsl_g = vsl ^ (vrw & 7);        // pre-swizzled source slot

    // hoist Q fragments
    bf16x8 qf[8];
    {
        const unsigned short* qrow = &Qb[(size_t)(q0 + wq * 16 + c) * IC_ + g * 8];
#pragma unroll
        for (int dc = 0; dc < 8; ++dc)
            qf[dc] = *(const bf16x8*)&qrow[dc * 32];
    }

    f32x4 yacc[16];
#pragma unroll
    for (int ds = 0; ds < 16; ++ds) yacc[ds] = (f32x4){0.f, 0.f, 0.f, 0.f};
    float m[4]    = {-1e30f, -1e30f, -1e30f, -1e30f};
    float lsum[4] = {0.f, 0.f, 0.f, 0.f};

    bf16x8 kst[8], vst[8];
    // prologue: stage tile 0
#pragma unroll
    for (int e = 0; e < 8; ++e)
        kst[e] = *(const bf16x8*)&Kb[(size_t)(krw + e * 8) * IC_ + (ksl_g << 3)];
#pragma unroll
    for (int e = 0; e < 8; ++e)
        vst[e] = *(const bf16x8*)&Vb[(size_t)(vrw + e * 32) * N_ + (vsl_g << 3)];
#pragma unroll
    for (int e = 0; e < 8; ++e)
        *(bf16x8*)&Ks[(krw + e * 8) * 256 + (ksl << 3)] = kst[e];
#pragma unroll
    for (int e = 0; e < 8; ++e)
        *(bf16x8*)&Vs[(vrw + e * 32) * 64 + (vsl << 3)] = vst[e];
    __syncthreads();

    const int NT = N_ / 64;   // 49
    for (int t = 0; t < NT; ++t) {
        // ---- prefetch next tile into regs (latency hides under compute) ----
        const int k0n = (t < NT - 1) ? (t + 1) * 64 : t * 64;
#pragma unroll
        for (int e = 0; e < 8; ++e)
            kst[e] = *(const bf16x8*)&Kb[(size_t)(k0n + krw + e * 8) * IC_ + (ksl_g << 3)];
#pragma unroll
        for (int e = 0; e < 8; ++e)
            vst[e] = *(const bf16x8*)&Vb[(size_t)(vrw + e * 32) * N_ + k0n + (vsl_g << 3)];

        // ---- QK^T: S[16 q][64 k] from Ks ----
        f32x4 sacc[4];
#pragma unroll
        for (int ks = 0; ks < 4; ++ks) sacc[ks] = (f32x4){0.f, 0.f, 0.f, 0.f};
#pragma unroll
        for (int ks = 0; ks < 4; ++ks)
#pragma unroll
            for (int dc = 0; dc < 8; ++dc) {
                const bf16x8 kf =
                    *(const bf16x8*)&Ks[(ks * 16 + c) * 256 + (((g + 4 * dc) ^ (c & 7)) << 3)];
                sacc[ks] = __builtin_amdgcn_mfma_f32_16x16x32_bf16(qf[dc], kf, sacc[ks], 0, 0, 0);
            }

        // ---- online softmax (lane owns rows q=4g+r, cols k=16ks+c) ----
        float mnew[4], sc[4], rsum[4];
#pragma unroll
        for (int r = 0; r < 4; ++r) {
            float rm = fmaxf(fmaxf(sacc[0][r], sacc[1][r]), fmaxf(sacc[2][r], sacc[3][r]));
            rm = fmaxf(rm, __shfl_xor(rm, 1));
            rm = fmaxf(rm, __shfl_xor(rm, 2));
            rm = fmaxf(rm, __shfl_xor(rm, 4));
            rm = fmaxf(rm, __shfl_xor(rm, 8));
            mnew[r] = fmaxf(m[r], rm);
            sc[r]   = __expf(m[r] - mnew[r]);
            m[r]    = mnew[r];
            rsum[r] = 0.f;
        }
        float p[4][4];
#pragma unroll
        for (int ks = 0; ks < 4; ++ks)
#pragma unroll
            for (int r = 0; r < 4; ++r) {
                p[ks][r] = __expf(sacc[ks][r] - mnew[r]);
                rsum[r] += p[ks][r];
            }
#pragma unroll
        for (int r = 0; r < 4; ++r) {
            rsum[r] += __shfl_xor(rsum[r], 1);
            rsum[r] += __shfl_xor(rsum[r], 2);
            rsum[r] += __shfl_xor(rsum[r], 4);
            rsum[r] += __shfl_xor(rsum[r], 8);
            lsum[r] = lsum[r] * sc[r] + rsum[r];
        }
#pragma unroll
        for (int ds = 0; ds < 16; ++ds)
#pragma unroll
            for (int r = 0; r < 4; ++r) yacc[ds][r] *= sc[r];

        // ---- P -> per-wave LDS (bf16, XOR-swizzled) ----
#pragma unroll
        for (int ks = 0; ks < 4; ++ks)
#pragma unroll
            for (int r = 0; r < 4; ++r) {
                const int q = 4 * g + r;
                const int k = ks * 16 + c;
                P_lds[wq][q * 64 + (k ^ ((q & 7) << 3))] = f2bf(p[ks][r]);
            }

        // ---- PV: Y += P[16x64] * V[64][256] from Vs ----
#pragma unroll
        for (int kc = 0; kc < 2; ++kc) {
            const bf16x8 pf =
                *(const bf16x8*)&P_lds[wq][c * 64 + ((kc * 32 + g * 8) ^ ((c & 7) << 3))];
#pragma unroll
            for (int ds = 0; ds < 16; ++ds) {
                const bf16x8 vf =
                    *(const bf16x8*)&Vs[(ds * 16 + c) * 64 + (((kc * 4 + g) ^ (c & 7)) << 3)];
                yacc[ds] = __builtin_amdgcn_mfma_f32_16x16x32_bf16(pf, vf, yacc[ds], 0, 0, 0);
            }
        }

        __syncthreads();   // all waves done reading Ks/Vs
        // ---- commit staged tile t+1 ----
#pragma unroll
        for (int e = 0; e < 8; ++e)
            *(bf16x8*)&Ks[(krw + e * 8) * 256 + (ksl << 3)] = kst[e];
#pragma unroll
        for (int e = 0; e < 8; ++e)
            *(bf16x8*)&Vs[(vrw + e * 32) * 64 + (vsl << 3)] = vst[e];
        __syncthreads();
    }

    // ---- epilogue: normalize, write Y fp32 [B,N,IC] ----
    float inv[4];
#pragma unroll
    for (int r = 0; r < 4; ++r) inv[r] = 1.f / lsum[r];
#pragma unroll
    for (int ds = 0; ds < 16; ++ds)
#pragma unroll
        for (int r = 0; r < 4; ++r)
            Y[((size_t)b * N_ + q0 + wq * 16 + 4 * g + r) * IC_ + ds * 16 + c] =
                yacc[ds][r] * inv[r];
}

// ---------------------------------------------------------------------------
// Kernel 3: wz projection. Z[b][c][n] = sum_i Y[b][n][i] * wz_w[c][i] + wz_b[c]
// ---------------------------------------------------------------------------
__global__ __launch_bounds__(256) void wz_kernel(
    const float* __restrict__ Y, const float* __restrict__ wzw,
    const float* __restrict__ wzb, float* __restrict__ Z)
{
    const int n0 = blockIdx.x * 64;
    const int c0 = blockIdx.y * 64;
    const int b  = blockIdx.z;

    __shared__ float As[16][68];
    __shared__ float Bs[16][68];

    const int tid = threadIdx.x;
    const int tx = tid & 15;
    const int ty = tid >> 4;

    float acc[4][4];
#pragma unroll
    for (int r = 0; r < 4; ++r)
#pragma unroll
        for (int s = 0; s < 4; ++s) acc[r][s] = 0.f;

    for (int k0 = 0; k0 < IC_; k0 += 16) {
#pragma unroll
        for (int e = 0; e < 4; ++e) {
            const int lin = tid + e * 256;
            const int row = lin >> 4, ii = lin & 15;
            As[ii][row] = wzw[(size_t)(c0 + row) * IC_ + k0 + ii];
            Bs[ii][row] = Y[((size_t)b * N_ + (n0 + row)) * IC_ + k0 + ii];
        }
        __syncthreads();
#pragma unroll
        for (int k = 0; k < 16; ++k) {
            float a[4], yv[4];
#pragma unroll
            for (int r = 0; r < 4; ++r) a[r] = As[k][ty * 4 + r];
#pragma unroll
            for (int s = 0; s < 4; ++s) yv[s] = Bs[k][tx * 4 + s];
#pragma unroll
            for (int r = 0; r < 4; ++r)
#pragma unroll
                for (int s = 0; s < 4; ++s) acc[r][s] += a[r] * yv[s];
        }
        __syncthreads();
    }

#pragma unroll
    for (int r = 0; r < 4; ++r) {
        const float br = wzb[c0 + ty * 4 + r];
        float4 o;
        o.x = acc[r][0] + br; o.y = acc[r][1] + br;
        o.z = acc[r][2] + br; o.w = acc[r][3] + br;
        *(float4*)&Z[((size_t)b * C_ + (c0 + ty * 4 + r)) * N_ + n0 + tx * 4] = o;
    }
}

// ---------------------------------------------------------------------------
// Kernel 4: per-channel batch stats (biased variance, double accum).
// ---------------------------------------------------------------------------
__global__ __launch_bounds__(256) void bn_stats_kernel(
    const float* __restrict__ Z, float* __restrict__ stats)
{
    const int c   = blockIdx.x;
    const int tid = threadIdx.x;
    double s = 0.0, s2 = 0.0;
    for (int b = 0; b < B_; ++b) {
        const float* p = Z + ((size_t)b * C_ + c) * N_;
        for (int n = tid; n < N_; n += 256) {
            const double v = (double)p[n];
            s += v; s2 += v * v;
        }
    }
    __shared__ double ls[256], ls2[256];
    ls[tid] = s; ls2[tid] = s2;
    __syncthreads();
    for (int off = 128; off > 0; off >>= 1) {
        if (tid < off) { ls[tid] += ls[tid + off]; ls2[tid] += ls2[tid + off]; }
        __syncthreads();
    }
    if (tid == 0) {
        const double M    = (double)B_ * (double)N_;
        const double mean = ls[0] / M;
        const double var  = ls2[0] / M - mean * mean;
        stats[c]      = (float)mean;
        stats[C_ + c] = (float)var;
    }
}

// ---------------------------------------------------------------------------
// Kernel 5: BN apply + residual, in place on d_out.
// ---------------------------------------------------------------------------
__global__ __launch_bounds__(256) void bn_apply_kernel(
    const float* __restrict__ Z, const float* __restrict__ x,
    const float* __restrict__ stats,
    const float* __restrict__ bnw, const float* __restrict__ bnb,
    float* __restrict__ out)
{
    const size_t total4 = (size_t)B_ * C_ * N_ / 4;
    const size_t i4 = (size_t)blockIdx.x * blockDim.x + threadIdx.x;
    if (i4 >= total4) return;
    const size_t i = i4 * 4;
    const int c = (int)((i / N_) % C_);
    const float mean = stats[c];
    const float var  = stats[C_ + c];
    const float sc = rsqrtf(var + 1e-5f) * bnw[c];
    const float sh = bnb[c] - mean * sc;
    const float4 z  = ((const float4*)Z)[i4];
    const float4 xv = ((const float4*)x)[i4];
    float4 o;
    o.x = z.x * sc + sh + xv.x;
    o.y = z.y * sc + sh + xv.y;
    o.z = z.z * sc + sh + xv.z;
    o.w = z.w * sc + sh + xv.w;
    ((float4*)out)[i4] = o;
}

// ---------------------------------------------------------------------------
extern "C" void kernel_launch(void* const* d_in, const int* in_sizes, int n_in,
                              void* d_out, int out_size, void* d_ws, size_t ws_size,
                              hipStream_t stream)
{
    const float* x   = (const float*)d_in[0];
    const float* tw  = (const float*)d_in[1];
    const float* tb  = (const float*)d_in[2];
    const float* pw  = (const float*)d_in[3];
    const float* pb  = (const float*)d_in[4];
    const float* gw  = (const float*)d_in[5];
    const float* gb  = (const float*)d_in[6];
    const float* wzw = (const float*)d_in[7];
    const float* wzb = (const float*)d_in[8];
    const float* bnw = (const float*)d_in[9];
    const float* bnb = (const float*)d_in[10];
    float* out = (float*)d_out;

    const size_t NIC = (size_t)B_ * N_ * IC_;      // 6,422,528
    unsigned short* Qw  = (unsigned short*)d_ws;   // bf16 [B,N,IC]
    unsigned short* Kw  = Qw + NIC;                // bf16 [B,N,IC]
    unsigned short* Vtw = Kw + NIC;                // bf16 [B,IC,N]
    float* Yw    = (float*)(Vtw + NIC);            // fp32 [B,N,IC]
    float* stats = Yw + NIC;                       // 2*C_
    float* Zb    = out;                            // d_out doubles as Z scratch

    qkv_kernel<<<dim3(N_ / 64, IC_ / 64, B_ * 3), 256, 0, stream>>>(
        x, tw, tb, pw, pb, gw, gb, Qw, Kw, Vtw);
    attn_kernel<<<dim3(B_, N_ / 64), 256, 0, stream>>>(Qw, Kw, Vtw, Yw);
    wz_kernel<<<dim3(N_ / 64, C_ / 64, B_), 256, 0, stream>>>(Yw, wzw, wzb, Zb);
    bn_stats_kernel<<<C_, 256, 0, stream>>>(Zb, stats);
    const int total4 = B_ * C_ * N_ / 4;
    bn_apply_kernel<<<(total4 + 255) / 256, 256, 0, stream>>>(Zb, x, stats, bnw, bnb, out);
}

// Round 4
// 440.729 us; speedup vs baseline: 10.0222x; 1.4480x over previous
//
#include <hip/hip_runtime.h>
#include <math.h>

#define B_  8
#define C_  512
#define N_  3136
#define IC_ 256

typedef __attribute__((ext_vector_type(8))) short bf16x8;
typedef __attribute__((ext_vector_type(4))) float f32x4;

static __device__ __forceinline__ unsigned short f2bf(float f) {
    unsigned int u = __builtin_bit_cast(unsigned int, f);
    u = (u + 0x7fffu + ((u >> 16) & 1u)) >> 16;   // RNE
    return (unsigned short)u;
}

// ---------------------------------------------------------------------------
// Kernel 0a: x [B,C,N] f32  ->  xb [B,N,C] bf16  (LDS transpose, pad 72)
// ---------------------------------------------------------------------------
__global__ __launch_bounds__(256) void xpose_kernel(
    const float* __restrict__ x, unsigned short* __restrict__ xb)
{
    const int n0 = blockIdx.x * 64;
    const int c0 = blockIdx.y * 64;
    const int b  = blockIdx.z;
    __shared__ unsigned short T[64][72];   // T[n][c]
    const int tid = threadIdx.x;
#pragma unroll
    for (int e = 0; e < 4; ++e) {
        const int idx = tid + e * 256;     // float4 index, 0..1023
        const int row = idx >> 4;          // c row 0..63
        const int c4  = idx & 15;          // n float4 group
        const float4 v = *(const float4*)&x[((size_t)b * C_ + c0 + row) * N_ + n0 + c4 * 4];
        T[c4 * 4 + 0][row] = f2bf(v.x);
        T[c4 * 4 + 1][row] = f2bf(v.y);
        T[c4 * 4 + 2][row] = f2bf(v.z);
        T[c4 * 4 + 3][row] = f2bf(v.w);
    }
    __syncthreads();
#pragma unroll
    for (int e = 0; e < 2; ++e) {
        const int s  = tid + e * 256;      // 512 slots: 64 n-rows x 8 slots
        const int nr = s >> 3;
        const int sl = s & 7;
        *(bf16x8*)&xb[((size_t)b * N_ + n0 + nr) * C_ + c0 + sl * 8] =
            *(const bf16x8*)&T[nr][sl * 8];
    }
}

// ---------------------------------------------------------------------------
// Kernel 0b: weight conversion -> Wcat[768][512] bf16 (theta|phi|g), wzwb bf16
// ---------------------------------------------------------------------------
__global__ __launch_bounds__(256) void wconv_kernel(
    const float* __restrict__ tw, const float* __restrict__ pw,
    const float* __restrict__ gw, const float* __restrict__ wzw,
    unsigned short* __restrict__ Wcat, unsigned short* __restrict__ wzwb)
{
    const int gid = blockIdx.x * 256 + threadIdx.x;   // 131072 total
    if (gid < 98304) {
        const int i  = gid >> 7;          // 0..767
        const int c4 = gid & 127;
        const float* src = (i < 256) ? &tw[(size_t)i * 512]
                         : (i < 512) ? &pw[(size_t)(i - 256) * 512]
                                     : &gw[(size_t)(i - 512) * 512];
        const float4 v = *(const float4*)&src[c4 * 4];
        ushort4 o; o.x = f2bf(v.x); o.y = f2bf(v.y); o.z = f2bf(v.z); o.w = f2bf(v.w);
        *(ushort4*)&Wcat[(size_t)i * 512 + c4 * 4] = o;
    } else {
        const int g2 = gid - 98304;       // 0..32767
        const int r  = g2 >> 6;
        const int c4 = g2 & 63;
        const float4 v = *(const float4*)&wzw[(size_t)r * 256 + c4 * 4];
        ushort4 o; o.x = f2bf(v.x); o.y = f2bf(v.y); o.z = f2bf(v.z); o.w = f2bf(v.w);
        *(ushort4*)&wzwb[(size_t)r * 256 + c4 * 4] = o;
    }
}

// ---------------------------------------------------------------------------
// Kernel 1: QKV projection, MFMA. out[n][i] = sum_c xb[n][c]*Wcat[i][c]+bias
// Tile 64n x 128i, BK=64, 4 waves (2m x 2n, wave=32x64). Reg-prefetch,
// XOR-swizzled LDS (LDS[row][s] = G[row][s^(row&7)], 16B slots).
// by: 0,1=theta(Q) 2,3=phi(K) 4,5=g(V->Vt transposed store).
// ---------------------------------------------------------------------------
__global__ __launch_bounds__(256, 2) void qkv_mfma_kernel(
    const unsigned short* __restrict__ xb, const unsigned short* __restrict__ Wcat,
    const float* __restrict__ tb, const float* __restrict__ pb,
    const float* __restrict__ gb,
    unsigned short* __restrict__ Q, unsigned short* __restrict__ K,
    unsigned short* __restrict__ Vt)
{
    const int n0 = blockIdx.x * 64;
    const int by = blockIdx.y;            // 0..5
    const int b  = blockIdx.z;
    const int i0 = by * 128;
    const int tid = threadIdx.x;
    const int wq = tid >> 6, lane = tid & 63;
    const int g = lane >> 4, c = lane & 15;
    const int wm = wq >> 1, wn = wq & 1;

    __shared__ unsigned short smem[12288];   // Asm[64][64] | Bsm[128][64]
    unsigned short* Asm = smem;
    unsigned short* Bsm = smem + 4096;

    const int srow = tid >> 3;   // staging base row (+32e)
    const int ssl  = tid & 7;    // staging slot

    f32x4 acc[2][4];
#pragma unroll
    for (int mb = 0; mb < 2; ++mb)
#pragma unroll
        for (int nb = 0; nb < 4; ++nb) acc[mb][nb] = (f32x4){0.f, 0.f, 0.f, 0.f};

    bf16x8 ast[2], bst[4];
    // prologue: stage c0=0
#pragma unroll
    for (int e = 0; e < 2; ++e) {
        const int row = srow + e * 32;
        ast[e] = *(const bf16x8*)&xb[((size_t)b * N_ + n0 + row) * C_ + ((ssl ^ (row & 7)) << 3)];
    }
#pragma unroll
    for (int e = 0; e < 4; ++e) {
        const int row = srow + e * 32;
        bst[e] = *(const bf16x8*)&Wcat[(size_t)(i0 + row) * C_ + ((ssl ^ (row & 7)) << 3)];
    }
#pragma unroll
    for (int e = 0; e < 2; ++e) *(bf16x8*)&Asm[(srow + e * 32) * 64 + ssl * 8] = ast[e];
#pragma unroll
    for (int e = 0; e < 4; ++e) *(bf16x8*)&Bsm[(srow + e * 32) * 64 + ssl * 8] = bst[e];
    __syncthreads();

    const int arow[2] = { wm * 32 + c, wm * 32 + 16 + c };
    const int brow[4] = { wn * 64 + c, wn * 64 + 16 + c, wn * 64 + 32 + c, wn * 64 + 48 + c };

    for (int s = 0; s < 8; ++s) {
        const int c0n = (s < 7) ? (s + 1) * 64 : s * 64;
#pragma unroll
        for (int e = 0; e < 2; ++e) {
            const int row = srow + e * 32;
            ast[e] = *(const bf16x8*)&xb[((size_t)b * N_ + n0 + row) * C_ + c0n + ((ssl ^ (row & 7)) << 3)];
        }
#pragma unroll
        for (int e = 0; e < 4; ++e) {
            const int row = srow + e * 32;
            bst[e] = *(const bf16x8*)&Wcat[(size_t)(i0 + row) * C_ + c0n + ((ssl ^ (row & 7)) << 3)];
        }
#pragma unroll
        for (int ks = 0; ks < 2; ++ks) {
            bf16x8 af[2], bfr[4];
            const int sl = ((ks << 2) | g);
#pragma unroll
            for (int mb = 0; mb < 2; ++mb)
                af[mb] = *(const bf16x8*)&Asm[arow[mb] * 64 + ((sl ^ (c & 7)) << 3)];
#pragma unroll
            for (int nb = 0; nb < 4; ++nb)
                bfr[nb] = *(const bf16x8*)&Bsm[brow[nb] * 64 + ((sl ^ (c & 7)) << 3)];
#pragma unroll
            for (int mb = 0; mb < 2; ++mb)
#pragma unroll
                for (int nb = 0; nb < 4; ++nb)
                    acc[mb][nb] = __builtin_amdgcn_mfma_f32_16x16x32_bf16(af[mb], bfr[nb], acc[mb][nb], 0, 0, 0);
        }
        __syncthreads();
#pragma unroll
        for (int e = 0; e < 2; ++e) *(bf16x8*)&Asm[(srow + e * 32) * 64 + ssl * 8] = ast[e];
#pragma unroll
        for (int e = 0; e < 4; ++e) *(bf16x8*)&Bsm[(srow + e * 32) * 64 + ssl * 8] = bst[e];
        __syncthreads();
    }

    const int proj = by >> 1;
    const float* bias = (proj == 0) ? tb : (proj == 1) ? pb : gb;
    const int icb = (by & 1) * 128;
    if (proj < 2) {
        unsigned short* out = (proj == 0) ? Q : K;
#pragma unroll
        for (int mb = 0; mb < 2; ++mb)
#pragma unroll
            for (int nb = 0; nb < 4; ++nb)
#pragma unroll
                for (int r = 0; r < 4; ++r) {
                    const int token = n0 + wm * 32 + mb * 16 + g * 4 + r;
                    const int ic = icb + wn * 64 + nb * 16 + c;
                    out[((size_t)b * N_ + token) * IC_ + ic] = f2bf(acc[mb][nb][r] + bias[ic]);
                }
    } else {
        // V: transpose via LDS (T[128][72]) then coalesced Vt stores
        unsigned short* T = smem;
#pragma unroll
        for (int mb = 0; mb < 2; ++mb)
#pragma unroll
            for (int nb = 0; nb < 4; ++nb)
#pragma unroll
                for (int r = 0; r < 4; ++r) {
                    const int il = wn * 64 + nb * 16 + c;
                    const int tl = wm * 32 + mb * 16 + g * 4 + r;
                    T[il * 72 + tl] = f2bf(acc[mb][nb][r] + bias[icb + il]);
                }
        __syncthreads();
#pragma unroll
        for (int e = 0; e < 4; ++e) {
            const int row = (tid >> 3) + e * 32;   // 0..127
            *(bf16x8*)&Vt[((size_t)b * IC_ + icb + row) * N_ + n0 + ((tid & 7) * 8)] =
                *(const bf16x8*)&T[row * 72 + (tid & 7) * 8];
        }
    }
}

// ---------------------------------------------------------------------------
// Kernel 2: MFMA flash attention. QBLK=112 (7 waves x 16q), KVBLK=64.
// LDS-staged K/V (XOR-swizzled), reg-prefetch pipeline, Y out bf16.
// ---------------------------------------------------------------------------
__global__ __launch_bounds__(448, 1) void attn_kernel(
    const unsigned short* __restrict__ Q, const unsigned short* __restrict__ K,
    const unsigned short* __restrict__ Vt, unsigned short* __restrict__ Y)
{
    const int b    = blockIdx.x;
    const int q0   = blockIdx.y * 112;
    const int tid  = threadIdx.x;
    const int wq   = tid >> 6;       // 0..6
    const int lane = tid & 63;
    const int g    = lane >> 4;
    const int c    = lane & 15;

    const unsigned short* Qb = Q  + (size_t)b * N_ * IC_;
    const unsigned short* Kb = K  + (size_t)b * N_ * IC_;
    const unsigned short* Vb = Vt + (size_t)b * IC_ * N_;

    __shared__ unsigned short Ks[64 * 256];        // 32 KB
    __shared__ unsigned short Vs[256 * 64];        // 32 KB
    __shared__ unsigned short P_lds[7][16 * 64];   // 14 KB

    bf16x8 qf[8];
    {
        const unsigned short* qrow = &Qb[(size_t)(q0 + wq * 16 + c) * IC_ + g * 8];
#pragma unroll
        for (int dc = 0; dc < 8; ++dc)
            qf[dc] = *(const bf16x8*)&qrow[dc * 32];
    }

    f32x4 yacc[16];
#pragma unroll
    for (int ds = 0; ds < 16; ++ds) yacc[ds] = (f32x4){0.f, 0.f, 0.f, 0.f};
    float m[4]    = {-1e30f, -1e30f, -1e30f, -1e30f};
    float lsum[4] = {0.f, 0.f, 0.f, 0.f};

    bf16x8 kst[5], vst[5];
    // prologue: stage tile 0 (2048 16B slots each for K and V, 448 threads)
#pragma unroll
    for (int e = 0; e < 5; ++e) {
        const int s = tid + e * 448;
        if (e < 4 || tid < 256) {
            const int kr = s >> 5, ksl = s & 31;
            kst[e] = *(const bf16x8*)&Kb[(size_t)kr * IC_ + ((ksl ^ (kr & 7)) << 3)];
            const int vr = s >> 3, vsl = s & 7;
            vst[e] = *(const bf16x8*)&Vb[(size_t)vr * N_ + ((vsl ^ (vr & 7)) << 3)];
        }
    }
#pragma unroll
    for (int e = 0; e < 5; ++e) {
        const int s = tid + e * 448;
        if (e < 4 || tid < 256) {
            *(bf16x8*)&Ks[(s >> 5) * 256 + (s & 31) * 8] = kst[e];
            *(bf16x8*)&Vs[(s >> 3) * 64 + (s & 7) * 8]   = vst[e];
        }
    }
    __syncthreads();

    const int NT = N_ / 64;   // 49
    for (int t = 0; t < NT; ++t) {
        const int k0n = (t < NT - 1) ? (t + 1) * 64 : t * 64;
#pragma unroll
        for (int e = 0; e < 5; ++e) {
            const int s = tid + e * 448;
            if (e < 4 || tid < 256) {
                const int kr = s >> 5, ksl = s & 31;
                kst[e] = *(const bf16x8*)&Kb[(size_t)(k0n + kr) * IC_ + ((ksl ^ (kr & 7)) << 3)];
                const int vr = s >> 3, vsl = s & 7;
                vst[e] = *(const bf16x8*)&Vb[(size_t)vr * N_ + k0n + ((vsl ^ (vr & 7)) << 3)];
            }
        }

        // ---- QK^T ----
        f32x4 sacc[4];
#pragma unroll
        for (int ks = 0; ks < 4; ++ks) sacc[ks] = (f32x4){0.f, 0.f, 0.f, 0.f};
#pragma unroll
        for (int ks = 0; ks < 4; ++ks)
#pragma unroll
            for (int dc = 0; dc < 8; ++dc) {
                const bf16x8 kf =
                    *(const bf16x8*)&Ks[(ks * 16 + c) * 256 + (((g + 4 * dc) ^ (c & 7)) << 3)];
                sacc[ks] = __builtin_amdgcn_mfma_f32_16x16x32_bf16(qf[dc], kf, sacc[ks], 0, 0, 0);
            }

        // ---- online softmax ----
        float mnew[4], sc[4], rsum[4];
#pragma unroll
        for (int r = 0; r < 4; ++r) {
            float rm = fmaxf(fmaxf(sacc[0][r], sacc[1][r]), fmaxf(sacc[2][r], sacc[3][r]));
            rm = fmaxf(rm, __shfl_xor(rm, 1));
            rm = fmaxf(rm, __shfl_xor(rm, 2));
            rm = fmaxf(rm, __shfl_xor(rm, 4));
            rm = fmaxf(rm, __shfl_xor(rm, 8));
            mnew[r] = fmaxf(m[r], rm);
            sc[r]   = __expf(m[r] - mnew[r]);
            m[r]    = mnew[r];
            rsum[r] = 0.f;
        }
        float p[4][4];
#pragma unroll
        for (int ks = 0; ks < 4; ++ks)
#pragma unroll
            for (int r = 0; r < 4; ++r) {
                p[ks][r] = __expf(sacc[ks][r] - mnew[r]);
                rsum[r] += p[ks][r];
            }
#pragma unroll
        for (int r = 0; r < 4; ++r) {
            rsum[r] += __shfl_xor(rsum[r], 1);
            rsum[r] += __shfl_xor(rsum[r], 2);
            rsum[r] += __shfl_xor(rsum[r], 4);
            rsum[r] += __shfl_xor(rsum[r], 8);
            lsum[r] = lsum[r] * sc[r] + rsum[r];
        }
#pragma unroll
        for (int ds = 0; ds < 16; ++ds)
#pragma unroll
            for (int r = 0; r < 4; ++r) yacc[ds][r] *= sc[r];

        // ---- P -> per-wave LDS ----
#pragma unroll
        for (int ks = 0; ks < 4; ++ks)
#pragma unroll
            for (int r = 0; r < 4; ++r) {
                const int q = 4 * g + r;
                const int k = ks * 16 + c;
                P_lds[wq][q * 64 + (k ^ ((q & 7) << 3))] = f2bf(p[ks][r]);
            }

        // ---- PV ----
#pragma unroll
        for (int kc = 0; kc < 2; ++kc) {
            const bf16x8 pf =
                *(const bf16x8*)&P_lds[wq][c * 64 + ((kc * 32 + g * 8) ^ ((c & 7) << 3))];
#pragma unroll
            for (int ds = 0; ds < 16; ++ds) {
                const bf16x8 vf =
                    *(const bf16x8*)&Vs[(ds * 16 + c) * 64 + (((kc * 4 + g) ^ (c & 7)) << 3)];
                yacc[ds] = __builtin_amdgcn_mfma_f32_16x16x32_bf16(pf, vf, yacc[ds], 0, 0, 0);
            }
        }

        __syncthreads();
#pragma unroll
        for (int e = 0; e < 5; ++e) {
            const int s = tid + e * 448;
            if (e < 4 || tid < 256) {
                *(bf16x8*)&Ks[(s >> 5) * 256 + (s & 31) * 8] = kst[e];
                *(bf16x8*)&Vs[(s >> 3) * 64 + (s & 7) * 8]   = vst[e];
            }
        }
        __syncthreads();
    }

    float inv[4];
#pragma unroll
    for (int r = 0; r < 4; ++r) inv[r] = 1.f / lsum[r];
#pragma unroll
    for (int ds = 0; ds < 16; ++ds)
#pragma unroll
        for (int r = 0; r < 4; ++r)
            Y[((size_t)b * N_ + q0 + wq * 16 + 4 * g + r) * IC_ + ds * 16 + c] =
                f2bf(yacc[ds][r] * inv[r]);
}

// ---------------------------------------------------------------------------
// Kernel 3: wz projection, MFMA. Z[b][c][n] = sum_i wzwb[c][i]*Yb[n][i]+wzb[c]
// Tile 128c x 64n, BK=64 (K=256: 4 steps), 4 waves (2c x 2n, wave=64x32).
// ---------------------------------------------------------------------------
__global__ __launch_bounds__(256, 2) void wz_mfma_kernel(
    const unsigned short* __restrict__ Yb, const unsigned short* __restrict__ wzwb,
    const float* __restrict__ wzb, float* __restrict__ Z)
{
    const int n0 = blockIdx.x * 64;
    const int c0 = blockIdx.y * 128;
    const int b  = blockIdx.z;
    const int tid = threadIdx.x;
    const int wq = tid >> 6, lane = tid & 63;
    const int g = lane >> 4, c = lane & 15;
    const int wm = wq >> 1, wn = wq & 1;

    __shared__ unsigned short smem[12288];   // Asm[128][64] | Bsm[64][64]
    unsigned short* Asm = smem;              // wzwb tile [c][i]
    unsigned short* Bsm = smem + 8192;       // Y tile    [n][i]

    const int srow = tid >> 3;
    const int ssl  = tid & 7;

    f32x4 acc[4][2];
#pragma unroll
    for (int mb = 0; mb < 4; ++mb)
#pragma unroll
        for (int nb = 0; nb < 2; ++nb) acc[mb][nb] = (f32x4){0.f, 0.f, 0.f, 0.f};

    bf16x8 ast[4], bst[2];
#pragma unroll
    for (int e = 0; e < 4; ++e) {
        const int row = srow + e * 32;
        ast[e] = *(const bf16x8*)&wzwb[(size_t)(c0 + row) * IC_ + ((ssl ^ (row & 7)) << 3)];
    }
#pragma unroll
    for (int e = 0; e < 2; ++e) {
        const int row = srow + e * 32;
        bst[e] = *(const bf16x8*)&Yb[((size_t)b * N_ + n0 + row) * IC_ + ((ssl ^ (row & 7)) << 3)];
    }
#pragma unroll
    for (int e = 0; e < 4; ++e) *(bf16x8*)&Asm[(srow + e * 32) * 64 + ssl * 8] = ast[e];
#pragma unroll
    for (int e = 0; e < 2; ++e) *(bf16x8*)&Bsm[(srow + e * 32) * 64 + ssl * 8] = bst[e];
    __syncthreads();

    const int arow[4] = { wm * 64 + c, wm * 64 + 16 + c, wm * 64 + 32 + c, wm * 64 + 48 + c };
    const int brow[2] = { wn * 32 + c, wn * 32 + 16 + c };

    for (int s = 0; s < 4; ++s) {
        const int k0n = (s < 3) ? (s + 1) * 64 : s * 64;
#pragma unroll
        for (int e = 0; e < 4; ++e) {
            const int row = srow + e * 32;
            ast[e] = *(const bf16x8*)&wzwb[(size_t)(c0 + row) * IC_ + k0n + ((ssl ^ (row & 7)) << 3)];
        }
#pragma unroll
        for (int e = 0; e < 2; ++e) {
            const int row = srow + e * 32;
            bst[e] = *(const bf16x8*)&Yb[((size_t)b * N_ + n0 + row) * IC_ + k0n + ((ssl ^ (row & 7)) << 3)];
        }
#pragma unroll
        for (int ks = 0; ks < 2; ++ks) {
            bf16x8 af[4], bfr[2];
            const int sl = ((ks << 2) | g);
#pragma unroll
            for (int mb = 0; mb < 4; ++mb)
                af[mb] = *(const bf16x8*)&Asm[arow[mb] * 64 + ((sl ^ (c & 7)) << 3)];
#pragma unroll
            for (int nb = 0; nb < 2; ++nb)
                bfr[nb] = *(const bf16x8*)&Bsm[brow[nb] * 64 + ((sl ^ (c & 7)) << 3)];
#pragma unroll
            for (int mb = 0; mb < 4; ++mb)
#pragma unroll
                for (int nb = 0; nb < 2; ++nb)
                    acc[mb][nb] = __builtin_amdgcn_mfma_f32_16x16x32_bf16(af[mb], bfr[nb], acc[mb][nb], 0, 0, 0);
        }
        __syncthreads();
#pragma unroll
        for (int e = 0; e < 4; ++e) *(bf16x8*)&Asm[(srow + e * 32) * 64 + ssl * 8] = ast[e];
#pragma unroll
        for (int e = 0; e < 2; ++e) *(bf16x8*)&Bsm[(srow + e * 32) * 64 + ssl * 8] = bst[e];
        __syncthreads();
    }

#pragma unroll
    for (int mb = 0; mb < 4; ++mb) {
#pragma unroll
        for (int r = 0; r < 4; ++r) {
            const int cg = c0 + wm * 64 + mb * 16 + g * 4 + r;
            const float bw = wzb[cg];
#pragma unroll
            for (int nb = 0; nb < 2; ++nb) {
                const int ng = n0 + wn * 32 + nb * 16 + c;
                Z[((size_t)b * C_ + cg) * N_ + ng] = acc[mb][nb][r] + bw;
            }
        }
    }
}

// ---------------------------------------------------------------------------
// Kernel 4: per-channel batch stats (biased variance, double accum).
// ---------------------------------------------------------------------------
__global__ __launch_bounds__(256) void bn_stats_kernel(
    const float* __restrict__ Z, float* __restrict__ stats)
{
    const int c   = blockIdx.x;
    const int tid = threadIdx.x;
    double s = 0.0, s2 = 0.0;
    for (int b = 0; b < B_; ++b) {
        const float* p = Z + ((size_t)b * C_ + c) * N_;
        for (int n = tid; n < N_; n += 256) {
            const double v = (double)p[n];
            s += v; s2 += v * v;
        }
    }
    __shared__ double ls[256], ls2[256];
    ls[tid] = s; ls2[tid] = s2;
    __syncthreads();
    for (int off = 128; off > 0; off >>= 1) {
        if (tid < off) { ls[tid] += ls[tid + off]; ls2[tid] += ls2[tid + off]; }
        __syncthreads();
    }
    if (tid == 0) {
        const double M    = (double)B_ * (double)N_;
        const double mean = ls[0] / M;
        const double var  = ls2[0] / M - mean * mean;
        stats[c]      = (float)mean;
        stats[C_ + c] = (float)var;
    }
}

// ---------------------------------------------------------------------------
// Kernel 5: BN apply + residual, in place on d_out.
// ---------------------------------------------------------------------------
__global__ __launch_bounds__(256) void bn_apply_kernel(
    const float* __restrict__ Z, const float* __restrict__ x,
    const float* __restrict__ stats,
    const float* __restrict__ bnw, const float* __restrict__ bnb,
    float* __restrict__ out)
{
    const size_t total4 = (size_t)B_ * C_ * N_ / 4;
    const size_t i4 = (size_t)blockIdx.x * blockDim.x + threadIdx.x;
    if (i4 >= total4) return;
    const size_t i = i4 * 4;
    const int c = (int)((i / N_) % C_);
    const float mean = stats[c];
    const float var  = stats[C_ + c];
    const float sc = rsqrtf(var + 1e-5f) * bnw[c];
    const float sh = bnb[c] - mean * sc;
    const float4 z  = ((const float4*)Z)[i4];
    const float4 xv = ((const float4*)x)[i4];
    float4 o;
    o.x = z.x * sc + sh + xv.x;
    o.y = z.y * sc + sh + xv.y;
    o.z = z.z * sc + sh + xv.z;
    o.w = z.w * sc + sh + xv.w;
    ((float4*)out)[i4] = o;
}

// ---------------------------------------------------------------------------
extern "C" void kernel_launch(void* const* d_in, const int* in_sizes, int n_in,
                              void* d_out, int out_size, void* d_ws, size_t ws_size,
                              hipStream_t stream)
{
    const float* x   = (const float*)d_in[0];
    const float* tw  = (const float*)d_in[1];
    const float* tb  = (const float*)d_in[2];
    const float* pw  = (const float*)d_in[3];
    const float* pb  = (const float*)d_in[4];
    const float* gw  = (const float*)d_in[5];
    const float* gb  = (const float*)d_in[6];
    const float* wzw = (const float*)d_in[7];
    const float* wzb = (const float*)d_in[8];
    const float* bnw = (const float*)d_in[9];
    const float* bnb = (const float*)d_in[10];
    float* out = (float*)d_out;

    const size_t NIC = (size_t)B_ * N_ * IC_;      // 6,422,528
    const size_t BNC = (size_t)B_ * N_ * C_;       // 12,845,056
    unsigned short* Qw   = (unsigned short*)d_ws;  // bf16 [B,N,IC]
    unsigned short* Kw   = Qw + NIC;               // bf16 [B,N,IC]
    unsigned short* Vtw  = Kw + NIC;               // bf16 [B,IC,N]
    unsigned short* Ybw  = Vtw + NIC;              // bf16 [B,N,IC]
    unsigned short* xbw  = Ybw + NIC;              // bf16 [B,N,C]
    unsigned short* Wcat = xbw + BNC;              // bf16 [768][512]
    unsigned short* wzwb = Wcat + 768 * 512;       // bf16 [512][256]
    float* stats = (float*)(wzwb + 512 * 256);     // 2*C_
    float* Zb    = out;                            // d_out doubles as Z scratch

    wconv_kernel<<<512, 256, 0, stream>>>(tw, pw, gw, wzw, Wcat, wzwb);
    xpose_kernel<<<dim3(N_ / 64, C_ / 64, B_), 256, 0, stream>>>(x, xbw);
    qkv_mfma_kernel<<<dim3(N_ / 64, 6, B_), 256, 0, stream>>>(
        xbw, Wcat, tb, pb, gb, Qw, Kw, Vtw);
    attn_kernel<<<dim3(B_, N_ / 112), 448, 0, stream>>>(Qw, Kw, Vtw, Ybw);
    wz_mfma_kernel<<<dim3(N_ / 64, C_ / 128, B_), 256, 0, stream>>>(Ybw, wzwb, wzb, Zb);
    bn_stats_kernel<<<C_, 256, 0, stream>>>(Zb, stats);
    const int total4 = B_ * C_ * N_ / 4;
    bn_apply_kernel<<<(total4 + 255) / 256, 256, 0, stream>>>(Zb, x, stats, bnw, bnb, out);
}